// Round 12
// baseline (4008.821 us; speedup 1.0000x reference)
//
#include <hip/hip_runtime.h>

typedef _Float16 h8 __attribute__((ext_vector_type(8)));
typedef float f32x4 __attribute__((ext_vector_type(4)));

#define NB 128
#define NT 2048
#define NIN 32
#define NS 32
#define NM 8
#define NE 64
#define NH 128
#define NH3 384
#define BPB 16

__device__ __forceinline__ float rcpf(float v) {
#if __has_builtin(__builtin_amdgcn_rcpf)
  return __builtin_amdgcn_rcpf(v);
#else
  return 1.0f / v;
#endif
}
__device__ __forceinline__ float sigmoid_f(float v) { return rcpf(1.0f + __expf(-v)); }
__device__ __forceinline__ float tanh_f(float v) { return 1.0f - 2.0f * rcpf(1.0f + __expf(2.0f * v)); }

#define MFMA(a, b, c) __builtin_amdgcn_mfma_f32_16x16x32_f16((a), (b), (c), 0, 0, 0)

// 16 batches per block, 8 blocks, everything in-loop via MFMA 16x16x32 f16.
__global__ __launch_bounds__(512, 1) void rnn_mfma(
    const float* __restrict__ gx, const float* __restrict__ gy,
    const float* __restrict__ W_enc, const float* __restrict__ b_enc,
    const float* __restrict__ W_in, const float* __restrict__ W_rec,
    const float* __restrict__ b_s, const float* __restrict__ W_x,
    const float* __restrict__ W_h, const float* __restrict__ b_x,
    const float* __restrict__ b_h, const float* __restrict__ W_gate,
    const float* __restrict__ b_gate, float* __restrict__ out) {
  const int tid = threadIdx.x;
  const int w = tid >> 6, l = tid & 63;
  const int col = l & 15, kg = l >> 4, rb = kg * 4;  // fragment coords
  const int bg = blockIdx.x;

  // LDS (all A-operand tiles XOR-swizzled; byte-addressed via char*)
  __shared__ __align__(16) _Float16 x_slab[64 * BPB * NIN];  // [d][b][i], ^((b&3)<<4)
  __shared__ __align__(16) _Float16 h_sh[BPB * NH];          // [b][j],   ^((b&7)<<4)
  __shared__ __align__(16) _Float16 enc_sh[BPB * NE];        // [b][e],   ^((b&7)<<4)
  __shared__ __align__(16) _Float16 kst_sh[BPB * NS];        // [b][s],   ^((b&3)<<4)
  __shared__ __align__(16) _Float16 ns_sh[BPB][NM][NS];
  __shared__ __align__(16) float g_sh[BPB][NM];
  __shared__ __align__(16) float err_sh[BPB];
  __shared__ __align__(16) float y_sh[BPB][128];

  char* xB = (char*)x_slab;
  char* hB = (char*)h_sh;
  char* eB = (char*)enc_sh;
  char* kB = (char*)kst_sh;

  // ---- B-fragment weights (B[k][col]: lane supplies col=l&15, k=(l>>4)*8+e) ----
  h8 whB[3][4], wxB[3][2], winB[2], wrecB[2], wencB, wgB[4];
  float bh3[3], bx3[3], wxe3[3], bs2[2], be = 0.f, bgv = 0.f;
  const int jc = 16 * w + col;  // z-column / h-dim owned by this lane (w<8 -> 0..127)
#pragma unroll
  for (int g = 0; g < 3; ++g) {
    const int j3 = g * NH + jc;
#pragma unroll
    for (int c = 0; c < 4; ++c)
#pragma unroll
      for (int e = 0; e < 8; ++e)
        whB[g][c][e] = (_Float16)W_h[(size_t)(c * 32 + kg * 8 + e) * NH3 + j3];
#pragma unroll
    for (int c = 0; c < 2; ++c)
#pragma unroll
      for (int e = 0; e < 8; ++e)
        wxB[g][c][e] = (_Float16)W_x[(size_t)(c * 32 + kg * 8 + e) * NH3 + j3];
    bh3[g] = b_h[j3];
    bx3[g] = b_x[j3];
    wxe3[g] = W_x[(size_t)NE * NH3 + j3];
  }
#pragma unroll
  for (int t16 = 0; t16 < 2; ++t16) {
    const int s = t16 * 16 + col;
#pragma unroll
    for (int e = 0; e < 8; ++e) {
      winB[t16][e] = (_Float16)W_in[w * 1024 + (kg * 8 + e) * 32 + s];
      wrecB[t16][e] = (_Float16)W_rec[w * 1024 + (kg * 8 + e) * 32 + s];
    }
    bs2[t16] = b_s[w * 32 + s];
  }
#pragma unroll
  for (int e = 0; e < 8; ++e) wencB[e] = (_Float16)0.f;
  if (w < 4) {
#pragma unroll
    for (int e = 0; e < 8; ++e)
      wencB[e] = (_Float16)W_enc[(kg * 8 + e) * NE + 16 * w + col];
    be = b_enc[16 * w + col];
  }
#pragma unroll
  for (int c = 0; c < 4; ++c)
#pragma unroll
    for (int e = 0; e < 8; ++e) wgB[c][e] = (_Float16)0.f;
  if (w == 4) {
#pragma unroll
    for (int c = 0; c < 4; ++c)
#pragma unroll
      for (int e = 0; e < 8; ++e)
        wgB[c][e] = (col < 8) ? (_Float16)W_gate[(c * 32 + kg * 8 + e) * NM + col]
                              : (_Float16)0.f;
    bgv = (col < 8) ? b_gate[col] : -1e30f;
  }

  // ---- zero state + prologue slab loads ----
  for (int i = tid; i < BPB * NH; i += 512) h_sh[i] = (_Float16)0.f;
  for (int i = tid; i < BPB * NM * NS; i += 512) ((_Float16*)ns_sh)[i] = (_Float16)0.f;

#define LOAD_X_SLAB(TB)                                                        \
  {                                                                            \
    for (int task = tid; task < 2048; task += 512) {                           \
      const int d = task >> 5;                                                 \
      const int bb = (task >> 1) & 15;                                         \
      const int hf = task & 1;                                                 \
      const float4* s4 = (const float4*)(gx +                                  \
          ((size_t)(bg * BPB + bb) * NT + ((TB) + d)) * NIN + hf * 16);        \
      const int rbase = d * 1024 + bb * 64;                                    \
      _Pragma("unroll")                                                        \
      for (int q2 = 0; q2 < 4; ++q2) {                                         \
        const float4 v = s4[q2];                                               \
        const int i0 = hf * 16 + q2 * 4;                                       \
        *(_Float16*)(xB + rbase + ((2 * (i0 + 0)) ^ ((bb & 3) << 4))) = (_Float16)v.x; \
        *(_Float16*)(xB + rbase + ((2 * (i0 + 1)) ^ ((bb & 3) << 4))) = (_Float16)v.y; \
        *(_Float16*)(xB + rbase + ((2 * (i0 + 2)) ^ ((bb & 3) << 4))) = (_Float16)v.z; \
        *(_Float16*)(xB + rbase + ((2 * (i0 + 3)) ^ ((bb & 3) << 4))) = (_Float16)v.w; \
      }                                                                        \
    }                                                                          \
  }

#define LOAD_Y_SLAB(TB)                                                        \
  {                                                                            \
    const int b_ = tid >> 5;                                                   \
    const int i0_ = (tid & 31) * 4;                                            \
    const float* yr = gy + (size_t)(bg * BPB + b_) * NT;                       \
    _Pragma("unroll")                                                          \
    for (int u = 0; u < 4; ++u) {                                              \
      const int idx = (TB)-1 + i0_ + u;                                        \
      y_sh[b_][i0_ + u] = yr[idx < 0 ? 0 : idx];                               \
    }                                                                          \
  }

  LOAD_X_SLAB(0)
  LOAD_Y_SLAB(0)
  __syncthreads();

  float h_prev[4] = {0.f, 0.f, 0.f, 0.f};

  for (int t = 0; t < NT; ++t) {
    // ================= P0: z/r/n MFMA | enc | gate+softmax =================
    h8 hA[4];
#pragma unroll
    for (int c = 0; c < 4; ++c) {
      const int off = ((l & 15) * 256 + (c * 64 + kg * 16)) ^ (((l & 15) & 7) << 4);
      hA[c] = *(const h8*)(hB + off);
    }
    f32x4 za = {bh3[0], bh3[0], bh3[0], bh3[0]};
    f32x4 ra = {bh3[1], bh3[1], bh3[1], bh3[1]};
    f32x4 na = {bh3[2], bh3[2], bh3[2], bh3[2]};
#pragma unroll
    for (int c = 0; c < 4; ++c) {
      za = MFMA(hA[c], whB[0][c], za);
      ra = MFMA(hA[c], whB[1][c], ra);
      na = MFMA(hA[c], whB[2][c], na);
    }
    const int xoff = (t & 63) * 1024 + (l & 15) * 64 + ((kg * 16) ^ (((l & 15) & 3) << 4));
    if (w < 4) {
      const h8 xA = *(const h8*)(xB + xoff);
      f32x4 ea = {be, be, be, be};
      ea = MFMA(xA, wencB, ea);
#pragma unroll
      for (int r = 0; r < 4; ++r) {
        const int brow = rb + r;
        const int eo = (brow * 128 + (16 * w + col) * 2) ^ ((brow & 7) << 4);
        *(_Float16*)(eB + eo) = (_Float16)tanh_f(ea[r]);
      }
    } else if (w == 4) {
      f32x4 ga = {bgv, bgv, bgv, bgv};
#pragma unroll
      for (int c = 0; c < 4; ++c) ga = MFMA(hA[c], wgB[c], ga);
      float mx[4], ev[4], sv[4];
#pragma unroll
      for (int r = 0; r < 4; ++r) mx[r] = ga[r];
#pragma unroll
      for (int mk = 1; mk <= 4; mk <<= 1)
#pragma unroll
        for (int r = 0; r < 4; ++r) mx[r] = fmaxf(mx[r], __shfl_xor(mx[r], mk, 64));
#pragma unroll
      for (int r = 0; r < 4; ++r) { ev[r] = __expf(ga[r] - mx[r]); sv[r] = ev[r]; }
#pragma unroll
      for (int mk = 1; mk <= 4; mk <<= 1)
#pragma unroll
        for (int r = 0; r < 4; ++r) sv[r] += __shfl_xor(sv[r], mk, 64);
      if (col < 8) {
#pragma unroll
        for (int r = 0; r < 4; ++r) g_sh[rb + r][col] = ev[r] * rcpf(sv[r]);
      }
    }
    __syncthreads();
    // ================= P1: xpre/xd MFMA | kst + err + out =================
    h8 encA[2];
#pragma unroll
    for (int c = 0; c < 2; ++c) {
      const int off = ((l & 15) * 128 + (c * 64 + kg * 16)) ^ (((l & 15) & 7) << 4);
      encA[c] = *(const h8*)(eB + off);
    }
    f32x4 xpa[3], xda[2];
#pragma unroll
    for (int g = 0; g < 3; ++g) {
      f32x4 acc = {bx3[g], bx3[g], bx3[g], bx3[g]};
#pragma unroll
      for (int c = 0; c < 2; ++c) acc = MFMA(encA[c], wxB[g][c], acc);
      xpa[g] = acc;
    }
    {
      const h8 xA = *(const h8*)(xB + xoff);
#pragma unroll
      for (int t16 = 0; t16 < 2; ++t16) {
        f32x4 acc = {bs2[t16], bs2[t16], bs2[t16], bs2[t16]};
        xda[t16] = MFMA(xA, winB[t16], acc);
      }
    }
    {
      const int b = tid >> 5, s = tid & 31;
      const float4* gv = (const float4*)&g_sh[b][0];
      const float4 g0 = gv[0], g1 = gv[1];
      float kv = g0.x * (float)ns_sh[b][0][s] + g0.y * (float)ns_sh[b][1][s] +
                 g0.z * (float)ns_sh[b][2][s] + g0.w * (float)ns_sh[b][3][s] +
                 g1.x * (float)ns_sh[b][4][s] + g1.y * (float)ns_sh[b][5][s] +
                 g1.z * (float)ns_sh[b][6][s] + g1.w * (float)ns_sh[b][7][s];
      const int ko = (b * 64 + s * 2) ^ ((b & 3) << 4);
      *(_Float16*)(kB + ko) = (_Float16)kv;
      if (s == 31) {
        err_sh[b] = (t == 0) ? 0.f : kv - y_sh[b][t & 127];
        if (t > 0) out[(size_t)(bg * BPB + b) * NT + t - 1] = kv;
      }
    }
    __syncthreads();
    // ================= P2: ns MFMA + GRU pointwise =================
    {
      const int off = ((l & 15) * 64 + ((kg * 16) ^ (((l & 15) & 3) << 4)));
      const h8 kstA = *(const h8*)(kB + off);
#pragma unroll
      for (int t16 = 0; t16 < 2; ++t16) {
        const f32x4 nsa = MFMA(kstA, wrecB[t16], xda[t16]);
#pragma unroll
        for (int r = 0; r < 4; ++r)
          ns_sh[rb + r][w][t16 * 16 + col] = (_Float16)tanh_f(nsa[r]);
      }
    }
    {
      const float4 errv = *(const float4*)&err_sh[rb];
      const float ee[4] = {errv.x, errv.y, errv.z, errv.w};
#pragma unroll
      for (int r = 0; r < 4; ++r) {
        const float z = sigmoid_f(za[r] + xpa[0][r] + ee[r] * wxe3[0]);
        const float rr = sigmoid_f(ra[r] + xpa[1][r] + ee[r] * wxe3[1]);
        const float n = tanh_f(xpa[2][r] + ee[r] * wxe3[2] + rr * na[r]);
        const float hnew = (1.f - z) * n + z * h_prev[r];
        h_prev[r] = hnew;
        const int brow = rb + r;
        const int ho = (brow * 256 + jc * 2) ^ ((brow & 7) << 4);
        *(_Float16*)(hB + ho) = (_Float16)hnew;
      }
    }
    if ((t & 63) == 63 && t + 1 < NT) LOAD_X_SLAB(t + 1)
    if ((t & 127) == 127 && t + 1 < NT) LOAD_Y_SLAB(t + 1)
    __syncthreads();
  }

  // ================= epilogue: pred(NT-1) =================
  if (w == 4) {
    h8 hA[4];
#pragma unroll
    for (int c = 0; c < 4; ++c) {
      const int off = ((l & 15) * 256 + (c * 64 + kg * 16)) ^ (((l & 15) & 7) << 4);
      hA[c] = *(const h8*)(hB + off);
    }
    f32x4 ga = {bgv, bgv, bgv, bgv};
#pragma unroll
    for (int c = 0; c < 4; ++c) ga = MFMA(hA[c], wgB[c], ga);
    float mx[4], ev[4], sv[4];
#pragma unroll
    for (int r = 0; r < 4; ++r) mx[r] = ga[r];
#pragma unroll
    for (int mk = 1; mk <= 4; mk <<= 1)
#pragma unroll
      for (int r = 0; r < 4; ++r) mx[r] = fmaxf(mx[r], __shfl_xor(mx[r], mk, 64));
#pragma unroll
    for (int r = 0; r < 4; ++r) { ev[r] = __expf(ga[r] - mx[r]); sv[r] = ev[r]; }
#pragma unroll
    for (int mk = 1; mk <= 4; mk <<= 1)
#pragma unroll
      for (int r = 0; r < 4; ++r) sv[r] += __shfl_xor(sv[r], mk, 64);
    if (col < 8) {
#pragma unroll
      for (int r = 0; r < 4; ++r) g_sh[rb + r][col] = ev[r] * rcpf(sv[r]);
    }
  }
  __syncthreads();
  {
    const int b = tid >> 5, s = tid & 31;
    if (s == 31) {
      const float4* gv = (const float4*)&g_sh[b][0];
      const float4 g0 = gv[0], g1 = gv[1];
      const float kv = g0.x * (float)ns_sh[b][0][31] + g0.y * (float)ns_sh[b][1][31] +
                       g0.z * (float)ns_sh[b][2][31] + g0.w * (float)ns_sh[b][3][31] +
                       g1.x * (float)ns_sh[b][4][31] + g1.y * (float)ns_sh[b][5][31] +
                       g1.z * (float)ns_sh[b][6][31] + g1.w * (float)ns_sh[b][7][31];
      out[(size_t)(bg * BPB + b) * NT + NT - 1] = kv;
    }
  }
}

extern "C" void kernel_launch(void* const* d_in, const int* in_sizes, int n_in,
                              void* d_out, int out_size, void* d_ws, size_t ws_size,
                              hipStream_t stream) {
  const float* x = (const float*)d_in[0];
  const float* y = (const float*)d_in[1];
  const float* W_enc = (const float*)d_in[2];
  const float* b_enc = (const float*)d_in[3];
  const float* W_in = (const float*)d_in[4];
  const float* W_rec = (const float*)d_in[5];
  const float* b_s = (const float*)d_in[6];
  const float* W_x = (const float*)d_in[7];
  const float* W_h = (const float*)d_in[8];
  const float* b_x = (const float*)d_in[9];
  const float* b_h = (const float*)d_in[10];
  const float* W_gate = (const float*)d_in[11];
  const float* b_gate = (const float*)d_in[12];
  float* out = (float*)d_out;

  rnn_mfma<<<dim3(NB / BPB), dim3(512), 0, stream>>>(
      x, y, W_enc, b_enc, W_in, W_rec, b_s, W_x, W_h, b_x, b_h, W_gate, b_gate,
      out);
}